// Round 4
// baseline (48.261 us; speedup 1.0000x reference)
//
#include <hip/hip_runtime.h>

// Problem shape (fixed by the reference):
//   k_cache/v_cache : (B, H, S, D)      f32
//   k_val/v_val     : (B, H, S_NEW, D)  f32
//   input_pos       : (S_NEW,)          i32  (distinct positions in [0,S))
//   flatten_index   : (B*H*HC,)         i32  (rows into the (B*H*S, D) view)
//   out             : [2, B, H, HC, D]  f32  (stacked K/V gathers AFTER scatter)
constexpr int B     = 4;
constexpr int H     = 32;
constexpr int S     = 4096;   // 2^12
constexpr int D     = 128;
constexpr int HC    = 1024;
constexpr int S_NEW = 512;

constexpr int NROWS = B * H * HC;                  // 131072 rows per tensor
constexpr int VPR   = D / 4;                       // 32 float4 per row
constexpr int LOG_VPR = 5;
constexpr int LOG_S   = 12;
constexpr unsigned TOTAL = (unsigned)NROWS * VPR;  // 4,194,304 vec-slots per tensor
constexpr unsigned HALF  = TOTAL / 2;
constexpr int BLOCK = 256;
constexpr int GRID  = 2048;                        // 8 blocks/CU (LDS: 16KiB -> 10 max)
constexpr unsigned CHUNKS = HALF / BLOCK;          // 8192; CHUNKS % GRID == 0 -> 4 iters

typedef float f32x4 __attribute__((ext_vector_type(4)));

// Fused kernel, grid-stride: per-block LDS inverse map built ONCE, then 4
// unrolled chunks. Each chunk: thread handles two (row, vec) slots -> 4
// independent 16B loads + 4 NT stores. 32 consecutive lanes stream one
// contiguous 512 B row; stores fully coalesced. NT stores keep the
// write-once output from evicting cacheable rows in L2.
__global__ __launch_bounds__(BLOCK) void fused_gather(
    const f32x4* __restrict__ k_cache, const f32x4* __restrict__ v_cache,
    const f32x4* __restrict__ k_val,   const f32x4* __restrict__ v_val,
    const int* __restrict__ input_pos, const int* __restrict__ fidx,
    f32x4* __restrict__ out)
{
    __shared__ int p2s[S];                       // 16 KiB inverse position map
    #pragma unroll
    for (int i = threadIdx.x; i < S; i += BLOCK) p2s[i] = -1;
    __syncthreads();
    #pragma unroll
    for (int i = threadIdx.x; i < S_NEW; i += BLOCK) p2s[input_pos[i]] = i;
    __syncthreads();

    #pragma unroll
    for (unsigned chunk = blockIdx.x; chunk < CHUNKS; chunk += GRID) {
        unsigned tid  = chunk * BLOCK + threadIdx.x;    // [0, HALF)
        unsigned vec  = tid & (VPR - 1);
        unsigned row0 = tid >> LOG_VPR;                 // [0, NROWS/2)
        unsigned row1 = row0 + (NROWS >> 1);

        int r0 = fidx[row0];
        int r1 = fidx[row1];
        int s0 = r0 & (S - 1),  s1 = r1 & (S - 1);
        int bh0 = r0 >> LOG_S,  bh1 = r1 >> LOG_S;
        int sl0 = p2s[s0],      sl1 = p2s[s1];          // wave-broadcast LDS reads

        size_t o0 = (sl0 >= 0) ? ((size_t)bh0 * S_NEW + (size_t)sl0) * VPR + vec
                               : (size_t)r0 * VPR + vec;
        size_t o1 = (sl1 >= 0) ? ((size_t)bh1 * S_NEW + (size_t)sl1) * VPR + vec
                               : (size_t)r1 * VPR + vec;
        const f32x4* kb0 = (sl0 >= 0) ? k_val : k_cache;
        const f32x4* vb0 = (sl0 >= 0) ? v_val : v_cache;
        const f32x4* kb1 = (sl1 >= 0) ? k_val : k_cache;
        const f32x4* vb1 = (sl1 >= 0) ? v_val : v_cache;

        // 4 independent in-flight loads (x4 iterations via unroll)
        f32x4 kq0 = kb0[o0];
        f32x4 kq1 = kb1[o1];
        f32x4 vq0 = vb0[o0];
        f32x4 vq1 = vb1[o1];

        __builtin_nontemporal_store(kq0, out + tid);
        __builtin_nontemporal_store(kq1, out + HALF + tid);
        __builtin_nontemporal_store(vq0, out + TOTAL + tid);
        __builtin_nontemporal_store(vq1, out + TOTAL + HALF + tid);
    }
}

extern "C" void kernel_launch(void* const* d_in, const int* in_sizes, int n_in,
                              void* d_out, int out_size, void* d_ws, size_t ws_size,
                              hipStream_t stream) {
    const float* k_cache   = (const float*)d_in[0];
    const float* v_cache   = (const float*)d_in[1];
    const float* k_val     = (const float*)d_in[2];
    const float* v_val     = (const float*)d_in[3];
    const int*   input_pos = (const int*)d_in[4];
    const int*   fidx      = (const int*)d_in[5];
    f32x4*       out       = (f32x4*)d_out;

    fused_gather<<<GRID, BLOCK, 0, stream>>>(
        (const f32x4*)k_cache, (const f32x4*)v_cache,
        (const f32x4*)k_val,   (const f32x4*)v_val,
        input_pos, fidx, out);
}

// Round 5
// 45.574 us; speedup vs baseline: 1.0590x; 1.0590x over previous
//
#include <hip/hip_runtime.h>

// Problem shape (fixed by the reference):
//   k_cache/v_cache : (B, H, S, D)      f32
//   k_val/v_val     : (B, H, S_NEW, D)  f32
//   input_pos       : (S_NEW,)          i32  (distinct positions in [0,S))
//   flatten_index   : (B*H*HC,)         i32  (rows into the (B*H*S, D) view)
//   out             : [2, B, H, HC, D]  f32  (stacked K/V gathers AFTER scatter)
constexpr int B     = 4;
constexpr int H     = 32;
constexpr int S     = 4096;   // 2^12
constexpr int D     = 128;
constexpr int HC    = 1024;
constexpr int S_NEW = 512;

constexpr int NROWS = B * H * HC;                  // 131072 rows per tensor
constexpr int VPR   = D / 4;                       // 32 float4 per row
constexpr int LOG_VPR = 5;
constexpr int LOG_S   = 12;
constexpr unsigned TOTAL = (unsigned)NROWS * VPR;  // 4,194,304 vec-slots per tensor
constexpr unsigned HALF  = TOTAL / 2;
constexpr int BLOCK = 512;                         // 4 blocks/CU, 64 KiB LDS/CU

typedef float f32x4 __attribute__((ext_vector_type(4)));

// Fused kernel (no inner loop — Round 4's grid-stride loop serialized on NT
// store completion via vmcnt register reuse). Each block builds the 4096-entry
// inverse position map in LDS once (BLOCK=512: init is 8 stores/thread,
// scatter exactly 1 iteration), then each thread handles two (row, vec)
// slots -> 4 independent 16 B loads + 4 NT stores. 32 consecutive lanes
// stream one contiguous 512 B row; stores fully coalesced. NT stores keep the
// write-once output from evicting cacheable rows in L2.
__global__ __launch_bounds__(BLOCK) void fused_gather(
    const f32x4* __restrict__ k_cache, const f32x4* __restrict__ v_cache,
    const f32x4* __restrict__ k_val,   const f32x4* __restrict__ v_val,
    const int* __restrict__ input_pos, const int* __restrict__ fidx,
    f32x4* __restrict__ out)
{
    __shared__ int p2s[S];                       // 16 KiB inverse position map
    #pragma unroll
    for (int i = threadIdx.x; i < S; i += BLOCK) p2s[i] = -1;
    __syncthreads();
    if (threadIdx.x < S_NEW) p2s[input_pos[threadIdx.x]] = (int)threadIdx.x;
    __syncthreads();

    unsigned tid  = blockIdx.x * BLOCK + threadIdx.x;   // [0, HALF)
    unsigned vec  = tid & (VPR - 1);
    unsigned row0 = tid >> LOG_VPR;                     // [0, NROWS/2)
    unsigned row1 = row0 + (NROWS >> 1);

    int r0 = fidx[row0];
    int r1 = fidx[row1];
    int s0 = r0 & (S - 1),  s1 = r1 & (S - 1);
    int bh0 = r0 >> LOG_S,  bh1 = r1 >> LOG_S;
    int sl0 = p2s[s0],      sl1 = p2s[s1];              // wave-broadcast LDS reads

    size_t o0 = (sl0 >= 0) ? ((size_t)bh0 * S_NEW + (size_t)sl0) * VPR + vec
                           : (size_t)r0 * VPR + vec;
    size_t o1 = (sl1 >= 0) ? ((size_t)bh1 * S_NEW + (size_t)sl1) * VPR + vec
                           : (size_t)r1 * VPR + vec;
    const f32x4* kb0 = (sl0 >= 0) ? k_val : k_cache;
    const f32x4* vb0 = (sl0 >= 0) ? v_val : v_cache;
    const f32x4* kb1 = (sl1 >= 0) ? k_val : k_cache;
    const f32x4* vb1 = (sl1 >= 0) ? v_val : v_cache;

    // 4 independent in-flight loads
    f32x4 kq0 = kb0[o0];
    f32x4 kq1 = kb1[o1];
    f32x4 vq0 = vb0[o0];
    f32x4 vq1 = vb1[o1];

    // out index for (tensor, row, vec) = tensor*TOTAL + row*VPR + vec
    __builtin_nontemporal_store(kq0, out + tid);
    __builtin_nontemporal_store(kq1, out + HALF + tid);
    __builtin_nontemporal_store(vq0, out + TOTAL + tid);
    __builtin_nontemporal_store(vq1, out + TOTAL + HALF + tid);
}

extern "C" void kernel_launch(void* const* d_in, const int* in_sizes, int n_in,
                              void* d_out, int out_size, void* d_ws, size_t ws_size,
                              hipStream_t stream) {
    const float* k_cache   = (const float*)d_in[0];
    const float* v_cache   = (const float*)d_in[1];
    const float* k_val     = (const float*)d_in[2];
    const float* v_val     = (const float*)d_in[3];
    const int*   input_pos = (const int*)d_in[4];
    const int*   fidx      = (const int*)d_in[5];
    f32x4*       out       = (f32x4*)d_out;

    unsigned blocks = HALF / BLOCK;   // 4096
    fused_gather<<<blocks, BLOCK, 0, stream>>>(
        (const f32x4*)k_cache, (const f32x4*)v_cache,
        (const f32x4*)k_val,   (const f32x4*)v_val,
        input_pos, fidx, out);
}